// Round 16
// baseline (193.977 us; speedup 1.0000x reference)
//
#include <hip/hip_runtime.h>
#include <math.h>

typedef unsigned short u16;
typedef unsigned int u32;
typedef __attribute__((ext_vector_type(4))) u16 u16x4;
typedef __attribute__((ext_vector_type(8))) short bf16x8;
typedef __attribute__((ext_vector_type(4))) float f32x4;

#define MFMA16(a, b, c) __builtin_amdgcn_mfma_f32_16x16x32_bf16(a, b, c, 0, 0, 0)

namespace {
constexpr int BATCH = 8;
constexpr int CDIM  = 512;
constexpr int PD    = 256;
constexpr int NPIX  = 4096;
constexpr int NTOT  = PD * NPIX;
constexpr float LOG2E = 1.44269504088896f;

// fp32 workspace region (float offsets)
constexpr int OFF_PART = 0;       // 8*64*2
constexpr int OFF_STAT = 2048;    // 8*2

// bf16 regions (u16 offsets from ws base)
constexpr size_t U16_BASE = 139264;                      // byte 278528
constexpr size_t QT_ELEMS = (size_t)BATCH * NPIX * 16;   // 524288
constexpr size_t V_ELEMS  = (size_t)BATCH * PD * NPIX;   // 8388608
constexpr size_t Y_ELEMS  = (size_t)BATCH * NPIX * CDIM; // 16777216
constexpr size_t WP_ELEMS = (size_t)CDIM * CDIM;         // 262144
constexpr size_t WQ_ELEMS = 288 * 256;                   // 73728

// tiled layouts: addr(r, k) = (k>>3)*(R*8) + r*8 + (k&7)
// xn: R=NPIX, K=PD   -> kblk stride 32768
// y : R=NPIX, K=CDIM -> kblk stride 32768
// wb: R=CDIM, K=CDIM -> kblk stride 4096
// wq: R=288,  K=PD   -> kblk stride 2304
// v : R=PD,   K=NPIX -> kblk stride 2048
} // namespace

__device__ __forceinline__ u16 f2bf(float f) {
    union { float f; u32 u; } v; v.f = f;
    return (u16)((v.u + 0x7fffu + ((v.u >> 16) & 1u)) >> 16);
}
__device__ __forceinline__ u32 cvtpk(float lo, float hi) {
    u32 r;
    asm("v_cvt_pk_bf16_f32 %0, %1, %2" : "=v"(r) : "v"(lo), "v"(hi));
    return r;
}
// native 2^x via intrinsic: single v_exp_f32 with proper TRANS hazard handling
__device__ __forceinline__ float fexp2(float x) {
    return __builtin_amdgcn_exp2f(x);
}

// ---------------- K1a: per-chunk partial sums for GroupNorm stats ----------
__global__ __launch_bounds__(256) void k_stats_partial(const float* __restrict__ x,
                                                       float* __restrict__ ws) {
    int b = blockIdx.y, chunk = blockIdx.x, t = threadIdx.x;
    const float4* x4 = reinterpret_cast<const float4*>(
        x + (size_t)b * CDIM * NPIX + (size_t)chunk * 16384);
    float s = 0.f, sq = 0.f;
#pragma unroll
    for (int i = 0; i < 16; ++i) {
        float4 v = x4[i * 256 + t];
        s  += v.x + v.y + v.z + v.w;
        sq += v.x * v.x + v.y * v.y + v.z * v.z + v.w * v.w;
    }
    for (int off = 32; off; off >>= 1) {
        s  += __shfl_down(s, off);
        sq += __shfl_down(sq, off);
    }
    __shared__ float red[8];
    int wid = t >> 6, lane = t & 63;
    if (lane == 0) { red[wid * 2] = s; red[wid * 2 + 1] = sq; }
    __syncthreads();
    if (t == 0) {
        float S = red[0] + red[2] + red[4] + red[6];
        float Q = red[1] + red[3] + red[5] + red[7];
        ws[OFF_PART + (b * 64 + chunk) * 2]     = S;
        ws[OFF_PART + (b * 64 + chunk) * 2 + 1] = Q;
    }
}

__global__ __launch_bounds__(64) void k_stats_final(float* __restrict__ ws) {
    int b = blockIdx.x, t = threadIdx.x;
    float s = ws[OFF_PART + (b * 64 + t) * 2];
    float q = ws[OFF_PART + (b * 64 + t) * 2 + 1];
    for (int off = 32; off; off >>= 1) {
        s += __shfl_down(s, off);
        q += __shfl_down(q, off);
    }
    if (t == 0) {
        float mean = s / (float)NTOT;
        float var  = q / (float)NTOT - mean * mean;
        ws[OFF_STAT + b * 2]     = mean;
        ws[OFF_STAT + b * 2 + 1] = rsqrtf(var + 1e-5f);
    }
}

// ------- merged fp32 -> bf16 convert into TILED layouts (wproj, wqkv) ------
__global__ __launch_bounds__(256) void k_cvt2(const float* __restrict__ wp,
                                              const float* __restrict__ wq,
                                              u16* __restrict__ wpb,
                                              u16* __restrict__ wqb) {
    int bx = blockIdx.x, t = threadIdx.x;
    if (bx < 256) {
        int i = bx * 1024 + t * 4;        // linear over [512][512]
        int o = i >> 9, k = i & 511;
        float4 v = *reinterpret_cast<const float4*>(wp + i);
        u16x4 out;
        out.x = f2bf(v.x); out.y = f2bf(v.y); out.z = f2bf(v.z); out.w = f2bf(v.w);
        *reinterpret_cast<u16x4*>(wpb + (k >> 3) * 4096 + o * 8 + (k & 7)) = out;
    } else {
        int i = (bx - 256) * 1024 + t * 4; // linear over [288][256]
        int o = i >> 8, k = i & 255;
        float4 v = *reinterpret_cast<const float4*>(wq + i);
        u16x4 out;
        out.x = f2bf(v.x); out.y = f2bf(v.y); out.z = f2bf(v.z); out.w = f2bf(v.w);
        *reinterpret_cast<u16x4*>(wqb + (k >> 3) * 2304 + o * 8 + (k & 7)) = out;
    }
}

// ------- K2: prep = GroupNorm(x1)->xn(tiled)  AND  silu(x2)->y(tiled) ------
__global__ __launch_bounds__(256) void k_prep(const float* __restrict__ x,
        const float* __restrict__ gnw, const float* __restrict__ gnb,
        const float* __restrict__ wsf, u16* __restrict__ xn, u16* __restrict__ yb) {
    int b = blockIdx.z, yy = blockIdx.y, n0 = blockIdx.x * 64, t = threadIdx.x;
    __shared__ u16 T[64][72];
    int c = t >> 2, nb = (t & 3) * 16;
    if (yy < 4) {
        int ca = yy * 64 + c;
        float mu = wsf[OFF_STAT + b * 2], rs = wsf[OFF_STAT + b * 2 + 1];
        float a = rs * gnw[ca];
        float sh = gnb[ca] - mu * a;
        const float* xb = x + ((size_t)b * CDIM + ca) * NPIX;
#pragma unroll
        for (int j = 0; j < 4; ++j) {
            float4 v = *reinterpret_cast<const float4*>(xb + n0 + nb + j * 4);
            T[nb + j * 4 + 0][c] = f2bf(v.x * a + sh);
            T[nb + j * 4 + 1][c] = f2bf(v.y * a + sh);
            T[nb + j * 4 + 2][c] = f2bf(v.z * a + sh);
            T[nb + j * 4 + 3][c] = f2bf(v.w * a + sh);
        }
        __syncthreads();
        int n = n0 + (t >> 2), cb = (t & 3) * 16;
        u16* dstb = xn + (size_t)b * NPIX * PD;
#pragma unroll
        for (int j = 0; j < 4; ++j) {
            int cg = yy * 64 + cb + j * 4;
            *reinterpret_cast<u16x4*>(dstb + (size_t)(cg >> 3) * 32768 + n * 8 + (cg & 7)) =
                *reinterpret_cast<u16x4*>(&T[t >> 2][cb + j * 4]);
        }
    } else {
        int c0 = (yy - 4) * 64;
        const float* xb = x + ((size_t)b * CDIM + PD + c0 + c) * NPIX;
#pragma unroll
        for (int j = 0; j < 4; ++j) {
            float4 v = *reinterpret_cast<const float4*>(xb + n0 + nb + j * 4);
            T[nb + j * 4 + 0][c] = f2bf(v.x / (1.f + __expf(-v.x)));
            T[nb + j * 4 + 1][c] = f2bf(v.y / (1.f + __expf(-v.y)));
            T[nb + j * 4 + 2][c] = f2bf(v.z / (1.f + __expf(-v.z)));
            T[nb + j * 4 + 3][c] = f2bf(v.w / (1.f + __expf(-v.w)));
        }
        __syncthreads();
        int n = n0 + (t >> 2), cb = (t & 3) * 16;
        u16* dstb = yb + (size_t)b * NPIX * CDIM;
#pragma unroll
        for (int j = 0; j < 4; ++j) {
            int cg = PD + c0 + cb + j * 4;
            *reinterpret_cast<u16x4*>(dstb + (size_t)(cg >> 3) * 32768 + n * 8 + (cg & 7)) =
                *reinterpret_cast<u16x4*>(&T[t >> 2][cb + j * 4]);
        }
    }
}

// ---------------- K3: qkv = w_qkv_bf16 @ xn (MFMA, tiled reads) ------------
__global__ __launch_bounds__(256) void k_qkv(const u16* __restrict__ xn,
        const u16* __restrict__ wq, const float* __restrict__ bqkv,
        u16* __restrict__ qt, u16* __restrict__ kt, u16* __restrict__ vb) {
    int b = blockIdx.z, o0 = blockIdx.y * 32, n0 = blockIdx.x * 256;
    int t = threadIdx.x, w = t >> 6, l = t & 63, lg = l >> 4, lr = l & 15;
    int nbase = n0 + w * 64;
    const u16* xnb = xn + (size_t)b * NPIX * PD;
    const f32x4 z4 = {0.f, 0.f, 0.f, 0.f};
    f32x4 acc[2][4];
#pragma unroll
    for (int i = 0; i < 2; ++i)
#pragma unroll
        for (int j = 0; j < 4; ++j) acc[i][j] = z4;

#pragma unroll
    for (int k0 = 0; k0 < PD; k0 += 32) {
        bf16x8 xf[4], wf[2];
#pragma unroll
        for (int nf = 0; nf < 4; ++nf)
            xf[nf] = *reinterpret_cast<const bf16x8*>(
                xnb + (size_t)((k0 >> 3) + lg) * 32768 + (nbase + nf * 16 + lr) * 8);
#pragma unroll
        for (int of = 0; of < 2; ++of)
            wf[of] = *reinterpret_cast<const bf16x8*>(
                wq + (size_t)((k0 >> 3) + lg) * 2304 + (o0 + of * 16 + lr) * 8);
#pragma unroll
        for (int of = 0; of < 2; ++of)
#pragma unroll
            for (int nf = 0; nf < 4; ++nf)
                acc[of][nf] = MFMA16(xf[nf], wf[of], acc[of][nf]);
    }

    if (o0 == 0) {
#pragma unroll
        for (int of = 0; of < 2; ++of) {
            int o = of * 16 + lr;
            float bias = bqkv[o];
            float sc = (of == 0) ? 0.25f * LOG2E : 1.0f;
            u16* dst = (of == 0) ? (qt + (size_t)b * NPIX * 16 + lr)
                                 : (kt + (size_t)b * NPIX * 16 + lr);
#pragma unroll
            for (int nf = 0; nf < 4; ++nf) {
#pragma unroll
                for (int r = 0; r < 4; ++r) {
                    int n = nbase + nf * 16 + 4 * lg + r;
                    dst[(size_t)n * 16] = f2bf((acc[of][nf][r] + bias) * sc);
                }
            }
        }
    } else {
        u16* vout = vb + (size_t)b * PD * NPIX;
#pragma unroll
        for (int of = 0; of < 2; ++of) {
            int c = o0 - 32 + of * 16 + lr;
            float bias = bqkv[32 + c];
#pragma unroll
            for (int nf = 0; nf < 4; ++nf) {
                u16x4 pw;
                pw.x = f2bf(acc[of][nf][0] + bias);
                pw.y = f2bf(acc[of][nf][1] + bias);
                pw.z = f2bf(acc[of][nf][2] + bias);
                pw.w = f2bf(acc[of][nf][3] + bias);
                // v tiled: elem(c, n) at (n>>3)*2048 + c*8 + (n&7)
                int nblk = (nbase >> 3) + nf * 2 + (lg >> 1);
                *reinterpret_cast<u16x4*>(
                    vout + (size_t)nblk * 2048 + c * 8 + (lg & 1) * 4) = pw;
            }
        }
    }
}

// ---------------- K4: fused flash PV (2-D PV wave split: 64c x 32n) --------
// r15 structure, one change: PV output decomposition per wave is now
// cs = w>>1 (64-c stripe) x nh = w&1 (32-n half). Each P fragment read from
// LDS feeds 4 MFMAs (was 2) -> ds_read_b128 per wave-iter 16 -> 8, halving
// the LDS-read pipe load (the 41% resource). V fragment loads double but are
// coalesced (tiled layout) and L2-resident (31 B/cy << 58 B/cy L2 budget).
// Score phase (band/mfb mapping), P layout, L-reduction unchanged.
__global__ __launch_bounds__(512) void k_attn_pv(const u16* __restrict__ qt,
        const u16* __restrict__ kt, const u16* __restrict__ vb,
        u16* __restrict__ yb) {
    int bid = blockIdx.x;
    int b = bid & 7, q0 = (bid >> 3) * 64;
    int t = threadIdx.x, w = t >> 6, l = t & 63, lg = l >> 4, lr = l & 15;
    int band = w & 3, mfb = w >> 2; // score mapping (unchanged)
    int cs = w >> 1, nh = w & 1;    // PV mapping (new)
    __shared__ u16 Pl[16384];      // flat: [buf 8192][half 4096][n*64+m swizzled]
    __shared__ float Ls[2][64];

    const u16* Qt = qt + ((size_t)b * NPIX + q0) * 16;

    const bf16x8 zf = {0, 0, 0, 0, 0, 0, 0, 0};
    bf16x8 qf = zf;
    if (lg < 2)
        qf = *reinterpret_cast<const bf16x8*>(Qt + (band * 16 + lr) * 16 + lg * 8);

    // hoisted pointers (stepped per iteration)
    const u16* kp  = kt + (size_t)b * NPIX * 16 + (size_t)(mfb * 16 + lr) * 16 + lg * 8;
    // V tiled: elem(c, m) at (m>>3)*2048 + c*8 + (m&7); lane reads m-slice lg*8
    const u16* vpc = vb + (size_t)b * PD * NPIX + lg * 2048 + (size_t)(cs * 64 + lr) * 8;

    float lp = 0.f;
    const f32x4 z4 = {0.f, 0.f, 0.f, 0.f};
    f32x4 acc[4][2];
#pragma unroll
    for (int cf = 0; cf < 4; ++cf)
#pragma unroll
        for (int nf = 0; nf < 2; ++nf) acc[cf][nf] = z4;

    int n = band * 16 + lr;
    int swz = (n & 7) << 3;
    int wrb = (n * 64 + mfb * 16 + 4 * lg) ^ swz; // f-variant: ^(i*32), +h*4096

    int bufo = 0;
    for (int it = 0; it < 32; ++it) {
        // ---- scores S^T = K·Q^T: 4 frags (2 halves x 2 mf) ----
#pragma unroll
        for (int f = 0; f < 4; ++f) {
            int h = f >> 1, i = f & 1;
            bf16x8 kf = zf;
            if (lg < 2)
                kf = *reinterpret_cast<const bf16x8*>(kp + h * 1024 + i * 512);
            f32x4 s = MFMA16(kf, qf, z4);
            float p0 = fexp2(s[0]);
            float p1 = fexp2(s[1]);
            float p2 = fexp2(s[2]);
            float p3 = fexp2(s[3]);
            lp += (p0 + p1) + (p2 + p3);
            uint2 pw;
            pw.x = cvtpk(p0, p1);
            pw.y = cvtpk(p2, p3);
            *reinterpret_cast<uint2*>(
                &Pl[bufo + h * 4096 + (wrb ^ (i * 32))]) = pw;
        }
        __syncthreads(); // P ready
        // ---- PV over 4 slices (h, ks): acc[c][n] += V[c][m] * P[n][m] ----
#pragma unroll
        for (int sl = 0; sl < 4; ++sl) {
            int h = sl >> 1, ks = sl & 1;
            bf16x8 vf[4];
#pragma unroll
            for (int cf = 0; cf < 4; ++cf)
                vf[cf] = *reinterpret_cast<const bf16x8*>(
                    vpc + cf * 128 + (h * 8 + ks * 4) * 2048);
#pragma unroll
            for (int nf = 0; nf < 2; ++nf) {
                int nn = nh * 32 + nf * 16 + lr;
                bf16x8 pf = *reinterpret_cast<const bf16x8*>(
                    &Pl[bufo + h * 4096 +
                        ((nn * 64 + ks * 32 + lg * 8) ^ ((nn & 7) << 3))]);
#pragma unroll
                for (int cf = 0; cf < 4; ++cf)
                    acc[cf][nf] = MFMA16(vf[cf], pf, acc[cf][nf]);
            }
        }
        kp += 2048; vpc += 32768;
        bufo ^= 8192;
    }
    // ---- finalize L: lane partial covers its (lg, mf-pair) m-slices ----
    lp += __shfl_xor(lp, 16);
    lp += __shfl_xor(lp, 32);
    if (l < 16) Ls[mfb][band * 16 + l] = lp; // waves mfb=0/1 hold complementary mf
    __syncthreads();
    float invl[2];
#pragma unroll
    for (int nf = 0; nf < 2; ++nf) {
        int nn = nh * 32 + nf * 16 + lr;
        invl[nf] = 1.f / (Ls[0][nn] + Ls[1][nn]);
    }
    // ---- epilogue: /L, SiLU, write y TILED: (c>>3)*32768 + n*8 + (c&7) ----
    u16* ybase = yb + (size_t)b * NPIX * CDIM;
#pragma unroll
    for (int nf = 0; nf < 2; ++nf) {
        int nq = q0 + nh * 32 + nf * 16 + lr;
#pragma unroll
        for (int cf = 0; cf < 4; ++cf) {
            int cg = cs * 64 + cf * 16 + 4 * lg;
            u16x4 pw;
#pragma unroll
            for (int r = 0; r < 4; ++r) {
                float v = acc[cf][nf][r] * invl[nf];
                pw[r] = f2bf(v / (1.f + __expf(-v)));
            }
            *reinterpret_cast<u16x4*>(
                ybase + (size_t)(cg >> 3) * 32768 + nq * 8 + (cg & 7)) = pw;
        }
    }
}

// -------- K6: out = w_proj_bf16 @ y_bf16 + b_proj (MFMA, tiled reads) ------
__global__ __launch_bounds__(256) void k_proj_mfma(const u16* __restrict__ wb,
        const u16* __restrict__ yb, const float* __restrict__ bproj,
        float* __restrict__ out) {
    int b = blockIdx.z, n0 = blockIdx.x * 128, o0 = blockIdx.y * 128;
    int t = threadIdx.x, w = t >> 6, l = t & 63, lg = l >> 4, lr = l & 15;
    int wo = w & 1, wn = w >> 1;
    int obase = o0 + wo * 64, nbase = n0 + wn * 64;
    const u16* ybb = yb + (size_t)b * NPIX * CDIM;
    const f32x4 z4 = {0.f, 0.f, 0.f, 0.f};
    f32x4 acc[4][4];
#pragma unroll
    for (int i = 0; i < 4; ++i)
#pragma unroll
        for (int j = 0; j < 4; ++j) acc[i][j] = z4;

    for (int k0 = 0; k0 < CDIM; k0 += 32) {
        bf16x8 af[4], bfr[4];
#pragma unroll
        for (int of = 0; of < 4; ++of)
            af[of] = *reinterpret_cast<const bf16x8*>(
                wb + (size_t)((k0 >> 3) + lg) * 4096 + (obase + of * 16 + lr) * 8);
#pragma unroll
        for (int nf = 0; nf < 4; ++nf)
            bfr[nf] = *reinterpret_cast<const bf16x8*>(
                ybb + (size_t)((k0 >> 3) + lg) * 32768 + (nbase + nf * 16 + lr) * 8);
#pragma unroll
        for (int of = 0; of < 4; ++of)
#pragma unroll
            for (int nf = 0; nf < 4; ++nf)
                acc[of][nf] = MFMA16(af[of], bfr[nf], acc[of][nf]);
    }
#pragma unroll
    for (int of = 0; of < 4; ++of) {
        int o = obase + of * 16 + 4 * lg;
#pragma unroll
        for (int r = 0; r < 4; ++r) {
            float bb = bproj[o + r];
#pragma unroll
            for (int nf = 0; nf < 4; ++nf)
                out[((size_t)b * CDIM + o + r) * NPIX + nbase + nf * 16 + lr] =
                    acc[of][nf][r] + bb;
        }
    }
}

extern "C" void kernel_launch(void* const* d_in, const int* in_sizes, int n_in,
                              void* d_out, int out_size, void* d_ws, size_t ws_size,
                              hipStream_t stream) {
    const float* x     = (const float*)d_in[0];
    const float* gnw   = (const float*)d_in[1];
    const float* gnb   = (const float*)d_in[2];
    const float* wqkv  = (const float*)d_in[3];
    const float* bqkv  = (const float*)d_in[4];
    const float* wproj = (const float*)d_in[5];
    const float* bproj = (const float*)d_in[6];
    float* out = (float*)d_out;
    float* wsf = (float*)d_ws;

    u16* qtp = (u16*)d_ws + U16_BASE;
    u16* ktp = qtp + QT_ELEMS;
    u16* vbp = ktp + QT_ELEMS;
    u16* ybp = vbp + V_ELEMS;
    u16* wbp = ybp + Y_ELEMS;
    u16* wqb = wbp + WP_ELEMS;
    u16* xnp = wqb + WQ_ELEMS;

    k_stats_partial<<<dim3(64, 8), 256, 0, stream>>>(x, wsf);
    k_stats_final<<<8, 64, 0, stream>>>(wsf);
    k_cvt2<<<328, 256, 0, stream>>>(wproj, wqkv, wbp, wqb);
    k_prep<<<dim3(64, 8, 8), 256, 0, stream>>>(x, gnw, gnb, wsf, xnp, ybp);
    k_qkv<<<dim3(16, 9, 8), 256, 0, stream>>>(xnp, wqb, bqkv, qtp, ktp, vbp);
    k_attn_pv<<<512, 512, 0, stream>>>(qtp, ktp, vbp, ybp);
    k_proj_mfma<<<dim3(32, 4, 8), 256, 0, stream>>>(wbp, ybp, bproj, out);
}

// Round 17
// 188.475 us; speedup vs baseline: 1.0292x; 1.0292x over previous
//
#include <hip/hip_runtime.h>
#include <math.h>

typedef unsigned short u16;
typedef unsigned int u32;
typedef __attribute__((ext_vector_type(4))) u16 u16x4;
typedef __attribute__((ext_vector_type(8))) short bf16x8;
typedef __attribute__((ext_vector_type(4))) float f32x4;

#define MFMA16(a, b, c) __builtin_amdgcn_mfma_f32_16x16x32_bf16(a, b, c, 0, 0, 0)

namespace {
constexpr int BATCH = 8;
constexpr int CDIM  = 512;
constexpr int PD    = 256;
constexpr int NPIX  = 4096;
constexpr int NTOT  = PD * NPIX;
constexpr float LOG2E = 1.44269504088896f;

// fp32 workspace region (float offsets)
constexpr int OFF_PART = 0;       // 8*64*2
constexpr int OFF_STAT = 2048;    // 8*2

// bf16 regions (u16 offsets from ws base)
constexpr size_t U16_BASE = 139264;                      // byte 278528
constexpr size_t QT_ELEMS = (size_t)BATCH * NPIX * 16;   // 524288
constexpr size_t V_ELEMS  = (size_t)BATCH * PD * NPIX;   // 8388608
constexpr size_t Y_ELEMS  = (size_t)BATCH * NPIX * CDIM; // 16777216
constexpr size_t WP_ELEMS = (size_t)CDIM * CDIM;         // 262144
constexpr size_t WQ_ELEMS = 288 * 256;                   // 73728

// tiled layouts: addr(r, k) = (k>>3)*(R*8) + r*8 + (k&7)
// xn: R=NPIX, K=PD   -> kblk stride 32768
// y : R=NPIX, K=CDIM -> kblk stride 32768
// wb: R=CDIM, K=CDIM -> kblk stride 4096
// wq: R=288,  K=PD   -> kblk stride 2304
// v : R=PD,   K=NPIX -> kblk stride 2048
} // namespace

__device__ __forceinline__ u16 f2bf(float f) {
    union { float f; u32 u; } v; v.f = f;
    return (u16)((v.u + 0x7fffu + ((v.u >> 16) & 1u)) >> 16);
}
__device__ __forceinline__ u32 cvtpk(float lo, float hi) {
    u32 r;
    asm("v_cvt_pk_bf16_f32 %0, %1, %2" : "=v"(r) : "v"(lo), "v"(hi));
    return r;
}
// native 2^x via intrinsic: single v_exp_f32 with proper TRANS hazard handling
__device__ __forceinline__ float fexp2(float x) {
    return __builtin_amdgcn_exp2f(x);
}

// ---------------- K1a: per-chunk partial sums for GroupNorm stats ----------
__global__ __launch_bounds__(256) void k_stats_partial(const float* __restrict__ x,
                                                       float* __restrict__ ws) {
    int b = blockIdx.y, chunk = blockIdx.x, t = threadIdx.x;
    const float4* x4 = reinterpret_cast<const float4*>(
        x + (size_t)b * CDIM * NPIX + (size_t)chunk * 16384);
    float s = 0.f, sq = 0.f;
#pragma unroll
    for (int i = 0; i < 16; ++i) {
        float4 v = x4[i * 256 + t];
        s  += v.x + v.y + v.z + v.w;
        sq += v.x * v.x + v.y * v.y + v.z * v.z + v.w * v.w;
    }
    for (int off = 32; off; off >>= 1) {
        s  += __shfl_down(s, off);
        sq += __shfl_down(sq, off);
    }
    __shared__ float red[8];
    int wid = t >> 6, lane = t & 63;
    if (lane == 0) { red[wid * 2] = s; red[wid * 2 + 1] = sq; }
    __syncthreads();
    if (t == 0) {
        float S = red[0] + red[2] + red[4] + red[6];
        float Q = red[1] + red[3] + red[5] + red[7];
        ws[OFF_PART + (b * 64 + chunk) * 2]     = S;
        ws[OFF_PART + (b * 64 + chunk) * 2 + 1] = Q;
    }
}

__global__ __launch_bounds__(64) void k_stats_final(float* __restrict__ ws) {
    int b = blockIdx.x, t = threadIdx.x;
    float s = ws[OFF_PART + (b * 64 + t) * 2];
    float q = ws[OFF_PART + (b * 64 + t) * 2 + 1];
    for (int off = 32; off; off >>= 1) {
        s += __shfl_down(s, off);
        q += __shfl_down(q, off);
    }
    if (t == 0) {
        float mean = s / (float)NTOT;
        float var  = q / (float)NTOT - mean * mean;
        ws[OFF_STAT + b * 2]     = mean;
        ws[OFF_STAT + b * 2 + 1] = rsqrtf(var + 1e-5f);
    }
}

// ------- merged fp32 -> bf16 convert into TILED layouts (wproj, wqkv) ------
__global__ __launch_bounds__(256) void k_cvt2(const float* __restrict__ wp,
                                              const float* __restrict__ wq,
                                              u16* __restrict__ wpb,
                                              u16* __restrict__ wqb) {
    int bx = blockIdx.x, t = threadIdx.x;
    if (bx < 256) {
        int i = bx * 1024 + t * 4;        // linear over [512][512]
        int o = i >> 9, k = i & 511;
        float4 v = *reinterpret_cast<const float4*>(wp + i);
        u16x4 out;
        out.x = f2bf(v.x); out.y = f2bf(v.y); out.z = f2bf(v.z); out.w = f2bf(v.w);
        *reinterpret_cast<u16x4*>(wpb + (k >> 3) * 4096 + o * 8 + (k & 7)) = out;
    } else {
        int i = (bx - 256) * 1024 + t * 4; // linear over [288][256]
        int o = i >> 8, k = i & 255;
        float4 v = *reinterpret_cast<const float4*>(wq + i);
        u16x4 out;
        out.x = f2bf(v.x); out.y = f2bf(v.y); out.z = f2bf(v.z); out.w = f2bf(v.w);
        *reinterpret_cast<u16x4*>(wqb + (k >> 3) * 2304 + o * 8 + (k & 7)) = out;
    }
}

// ------- K2: prep = GroupNorm(x1)->xn(tiled)  AND  silu(x2)->y(tiled) ------
__global__ __launch_bounds__(256) void k_prep(const float* __restrict__ x,
        const float* __restrict__ gnw, const float* __restrict__ gnb,
        const float* __restrict__ wsf, u16* __restrict__ xn, u16* __restrict__ yb) {
    int b = blockIdx.z, yy = blockIdx.y, n0 = blockIdx.x * 64, t = threadIdx.x;
    __shared__ u16 T[64][72];
    int c = t >> 2, nb = (t & 3) * 16;
    if (yy < 4) {
        int ca = yy * 64 + c;
        float mu = wsf[OFF_STAT + b * 2], rs = wsf[OFF_STAT + b * 2 + 1];
        float a = rs * gnw[ca];
        float sh = gnb[ca] - mu * a;
        const float* xb = x + ((size_t)b * CDIM + ca) * NPIX;
#pragma unroll
        for (int j = 0; j < 4; ++j) {
            float4 v = *reinterpret_cast<const float4*>(xb + n0 + nb + j * 4);
            T[nb + j * 4 + 0][c] = f2bf(v.x * a + sh);
            T[nb + j * 4 + 1][c] = f2bf(v.y * a + sh);
            T[nb + j * 4 + 2][c] = f2bf(v.z * a + sh);
            T[nb + j * 4 + 3][c] = f2bf(v.w * a + sh);
        }
        __syncthreads();
        int n = n0 + (t >> 2), cb = (t & 3) * 16;
        u16* dstb = xn + (size_t)b * NPIX * PD;
#pragma unroll
        for (int j = 0; j < 4; ++j) {
            int cg = yy * 64 + cb + j * 4;
            *reinterpret_cast<u16x4*>(dstb + (size_t)(cg >> 3) * 32768 + n * 8 + (cg & 7)) =
                *reinterpret_cast<u16x4*>(&T[t >> 2][cb + j * 4]);
        }
    } else {
        int c0 = (yy - 4) * 64;
        const float* xb = x + ((size_t)b * CDIM + PD + c0 + c) * NPIX;
#pragma unroll
        for (int j = 0; j < 4; ++j) {
            float4 v = *reinterpret_cast<const float4*>(xb + n0 + nb + j * 4);
            T[nb + j * 4 + 0][c] = f2bf(v.x / (1.f + __expf(-v.x)));
            T[nb + j * 4 + 1][c] = f2bf(v.y / (1.f + __expf(-v.y)));
            T[nb + j * 4 + 2][c] = f2bf(v.z / (1.f + __expf(-v.z)));
            T[nb + j * 4 + 3][c] = f2bf(v.w / (1.f + __expf(-v.w)));
        }
        __syncthreads();
        int n = n0 + (t >> 2), cb = (t & 3) * 16;
        u16* dstb = yb + (size_t)b * NPIX * CDIM;
#pragma unroll
        for (int j = 0; j < 4; ++j) {
            int cg = PD + c0 + cb + j * 4;
            *reinterpret_cast<u16x4*>(dstb + (size_t)(cg >> 3) * 32768 + n * 8 + (cg & 7)) =
                *reinterpret_cast<u16x4*>(&T[t >> 2][cb + j * 4]);
        }
    }
}

// ---------------- K3: qkv = w_qkv_bf16 @ xn (MFMA, tiled reads) ------------
__global__ __launch_bounds__(256) void k_qkv(const u16* __restrict__ xn,
        const u16* __restrict__ wq, const float* __restrict__ bqkv,
        u16* __restrict__ qt, u16* __restrict__ kt, u16* __restrict__ vb) {
    int b = blockIdx.z, o0 = blockIdx.y * 32, n0 = blockIdx.x * 256;
    int t = threadIdx.x, w = t >> 6, l = t & 63, lg = l >> 4, lr = l & 15;
    int nbase = n0 + w * 64;
    const u16* xnb = xn + (size_t)b * NPIX * PD;
    const f32x4 z4 = {0.f, 0.f, 0.f, 0.f};
    f32x4 acc[2][4];
#pragma unroll
    for (int i = 0; i < 2; ++i)
#pragma unroll
        for (int j = 0; j < 4; ++j) acc[i][j] = z4;

#pragma unroll
    for (int k0 = 0; k0 < PD; k0 += 32) {
        bf16x8 xf[4], wf[2];
#pragma unroll
        for (int nf = 0; nf < 4; ++nf)
            xf[nf] = *reinterpret_cast<const bf16x8*>(
                xnb + (size_t)((k0 >> 3) + lg) * 32768 + (nbase + nf * 16 + lr) * 8);
#pragma unroll
        for (int of = 0; of < 2; ++of)
            wf[of] = *reinterpret_cast<const bf16x8*>(
                wq + (size_t)((k0 >> 3) + lg) * 2304 + (o0 + of * 16 + lr) * 8);
#pragma unroll
        for (int of = 0; of < 2; ++of)
#pragma unroll
            for (int nf = 0; nf < 4; ++nf)
                acc[of][nf] = MFMA16(xf[nf], wf[of], acc[of][nf]);
    }

    if (o0 == 0) {
#pragma unroll
        for (int of = 0; of < 2; ++of) {
            int o = of * 16 + lr;
            float bias = bqkv[o];
            float sc = (of == 0) ? 0.25f * LOG2E : 1.0f;
            u16* dst = (of == 0) ? (qt + (size_t)b * NPIX * 16 + lr)
                                 : (kt + (size_t)b * NPIX * 16 + lr);
#pragma unroll
            for (int nf = 0; nf < 4; ++nf) {
#pragma unroll
                for (int r = 0; r < 4; ++r) {
                    int n = nbase + nf * 16 + 4 * lg + r;
                    dst[(size_t)n * 16] = f2bf((acc[of][nf][r] + bias) * sc);
                }
            }
        }
    } else {
        u16* vout = vb + (size_t)b * PD * NPIX;
#pragma unroll
        for (int of = 0; of < 2; ++of) {
            int c = o0 - 32 + of * 16 + lr;
            float bias = bqkv[32 + c];
#pragma unroll
            for (int nf = 0; nf < 4; ++nf) {
                u16x4 pw;
                pw.x = f2bf(acc[of][nf][0] + bias);
                pw.y = f2bf(acc[of][nf][1] + bias);
                pw.z = f2bf(acc[of][nf][2] + bias);
                pw.w = f2bf(acc[of][nf][3] + bias);
                // v tiled: elem(c, n) at (n>>3)*2048 + c*8 + (n&7)
                int nblk = (nbase >> 3) + nf * 2 + (lg >> 1);
                *reinterpret_cast<u16x4*>(
                    vout + (size_t)nblk * 2048 + c * 8 + (lg & 1) * 4) = pw;
            }
        }
    }
}

// ---------------- K4: fused flash PV (r15 structure; 256 m per iteration) --
// Geometry extension along the proven barrier-amortization gradient:
// 16 iters x 256 m (was 32 x 128). Pl doubles to 2 buf x 4 halves x 4096 u16
// (64 KB; 2 blocks/CU = 132 KB LDS, occupancy unchanged - grid-limited).
// Score loop 8 frags (4 halves x 2 mf), PV 8 slices. All mappings, swizzle,
// L-reduction, epilogue identical to r15 (the 110 us kernel).
__global__ __launch_bounds__(512) void k_attn_pv(const u16* __restrict__ qt,
        const u16* __restrict__ kt, const u16* __restrict__ vb,
        u16* __restrict__ yb) {
    int bid = blockIdx.x;
    int b = bid & 7, q0 = (bid >> 3) * 64;
    int t = threadIdx.x, w = t >> 6, l = t & 63, lg = l >> 4, lr = l & 15;
    int band = w & 3, mfb = w >> 2; // wave scores band `band`, mf in {mfb, mfb+2}
    __shared__ u16 Pl[32768];      // flat: [buf 16384][half 4096][n*64+m swizzled]
    __shared__ float Ls[2][64];

    const u16* Qt = qt + ((size_t)b * NPIX + q0) * 16;

    const bf16x8 zf = {0, 0, 0, 0, 0, 0, 0, 0};
    bf16x8 qf = zf;
    if (lg < 2)
        qf = *reinterpret_cast<const bf16x8*>(Qt + (band * 16 + lr) * 16 + lg * 8);

    // hoisted pointers (stepped per iteration)
    const u16* kp  = kt + (size_t)b * NPIX * 16 + (size_t)(mfb * 16 + lr) * 16 + lg * 8;
    // V tiled: elem(c, m) at (m>>3)*2048 + c*8 + (m&7); lane reads m-slice lg*8
    const u16* vp0 = vb + (size_t)b * PD * NPIX + lg * 2048 + (size_t)(w * 32 + lr) * 8;
    const u16* vp1 = vp0 + 128; // +16 c

    float lp = 0.f;
    const f32x4 z4 = {0.f, 0.f, 0.f, 0.f};
    f32x4 acc[2][4];
#pragma unroll
    for (int cf = 0; cf < 2; ++cf)
#pragma unroll
        for (int nf = 0; nf < 4; ++nf) acc[cf][nf] = z4;

    int n = band * 16 + lr;
    int swz = (n & 7) << 3;
    int wrb = (n * 64 + mfb * 16 + 4 * lg) ^ swz; // f-variant: ^(i*32), +h*4096

    int bufo = 0;
    for (int it = 0; it < 16; ++it) {
        // ---- scores S^T = K·Q^T: 8 frags (4 halves x 2 mf) ----
#pragma unroll
        for (int f = 0; f < 8; ++f) {
            int h = f >> 1, i = f & 1;
            bf16x8 kf = zf;
            if (lg < 2)
                kf = *reinterpret_cast<const bf16x8*>(kp + h * 1024 + i * 512);
            f32x4 s = MFMA16(kf, qf, z4);
            float p0 = fexp2(s[0]);
            float p1 = fexp2(s[1]);
            float p2 = fexp2(s[2]);
            float p3 = fexp2(s[3]);
            lp += (p0 + p1) + (p2 + p3);
            uint2 pw;
            pw.x = cvtpk(p0, p1);
            pw.y = cvtpk(p2, p3);
            *reinterpret_cast<uint2*>(
                &Pl[bufo + h * 4096 + (wrb ^ (i * 32))]) = pw;
        }
        __syncthreads(); // P ready
        // ---- PV over 8 slices (h, ks): acc[c][n] += V[c][m] * P[n][m] ----
#pragma unroll
        for (int sl = 0; sl < 8; ++sl) {
            int h = sl >> 1, ks = sl & 1;
            bf16x8 vf0 = *reinterpret_cast<const bf16x8*>(
                vp0 + (h * 8 + ks * 4) * 2048);
            bf16x8 vf1 = *reinterpret_cast<const bf16x8*>(
                vp1 + (h * 8 + ks * 4) * 2048);
#pragma unroll
            for (int nf = 0; nf < 4; ++nf) {
                int nn = nf * 16 + lr;
                bf16x8 pf = *reinterpret_cast<const bf16x8*>(
                    &Pl[bufo + h * 4096 +
                        ((nn * 64 + ks * 32 + lg * 8) ^ ((nn & 7) << 3))]);
                acc[0][nf] = MFMA16(vf0, pf, acc[0][nf]);
                acc[1][nf] = MFMA16(vf1, pf, acc[1][nf]);
            }
        }
        kp += 4096; vp0 += 65536; vp1 += 65536;
        bufo ^= 16384;
    }
    // ---- finalize L: lane partial covers its (lg, mf-pair) m-slices ----
    lp += __shfl_xor(lp, 16);
    lp += __shfl_xor(lp, 32);
    if (l < 16) Ls[mfb][band * 16 + l] = lp; // waves mfb=0/1 hold complementary mf
    __syncthreads();
    float invl[4];
#pragma unroll
    for (int nf = 0; nf < 4; ++nf)
        invl[nf] = 1.f / (Ls[0][nf * 16 + lr] + Ls[1][nf * 16 + lr]);
    // ---- epilogue: /L, SiLU, write y TILED: (c>>3)*32768 + n*8 + (c&7) ----
    u16* ybase = yb + (size_t)b * NPIX * CDIM;
#pragma unroll
    for (int nf = 0; nf < 4; ++nf) {
        int nq = q0 + nf * 16 + lr;
#pragma unroll
        for (int cf = 0; cf < 2; ++cf) {
            int cg = w * 32 + cf * 16 + 4 * lg;
            u16x4 pw;
#pragma unroll
            for (int r = 0; r < 4; ++r) {
                float v = acc[cf][nf][r] * invl[nf];
                pw[r] = f2bf(v / (1.f + __expf(-v)));
            }
            *reinterpret_cast<u16x4*>(
                ybase + (size_t)(cg >> 3) * 32768 + nq * 8 + (cg & 7)) = pw;
        }
    }
}

// -------- K6: out = w_proj_bf16 @ y_bf16 + b_proj (MFMA, tiled reads) ------
__global__ __launch_bounds__(256) void k_proj_mfma(const u16* __restrict__ wb,
        const u16* __restrict__ yb, const float* __restrict__ bproj,
        float* __restrict__ out) {
    int b = blockIdx.z, n0 = blockIdx.x * 128, o0 = blockIdx.y * 128;
    int t = threadIdx.x, w = t >> 6, l = t & 63, lg = l >> 4, lr = l & 15;
    int wo = w & 1, wn = w >> 1;
    int obase = o0 + wo * 64, nbase = n0 + wn * 64;
    const u16* ybb = yb + (size_t)b * NPIX * CDIM;
    const f32x4 z4 = {0.f, 0.f, 0.f, 0.f};
    f32x4 acc[4][4];
#pragma unroll
    for (int i = 0; i < 4; ++i)
#pragma unroll
        for (int j = 0; j < 4; ++j) acc[i][j] = z4;

    for (int k0 = 0; k0 < CDIM; k0 += 32) {
        bf16x8 af[4], bfr[4];
#pragma unroll
        for (int of = 0; of < 4; ++of)
            af[of] = *reinterpret_cast<const bf16x8*>(
                wb + (size_t)((k0 >> 3) + lg) * 4096 + (obase + of * 16 + lr) * 8);
#pragma unroll
        for (int nf = 0; nf < 4; ++nf)
            bfr[nf] = *reinterpret_cast<const bf16x8*>(
                ybb + (size_t)((k0 >> 3) + lg) * 32768 + (nbase + nf * 16 + lr) * 8);
#pragma unroll
        for (int of = 0; of < 4; ++of)
#pragma unroll
            for (int nf = 0; nf < 4; ++nf)
                acc[of][nf] = MFMA16(af[of], bfr[nf], acc[of][nf]);
    }
#pragma unroll
    for (int of = 0; of < 4; ++of) {
        int o = obase + of * 16 + 4 * lg;
#pragma unroll
        for (int r = 0; r < 4; ++r) {
            float bb = bproj[o + r];
#pragma unroll
            for (int nf = 0; nf < 4; ++nf)
                out[((size_t)b * CDIM + o + r) * NPIX + nbase + nf * 16 + lr] =
                    acc[of][nf][r] + bb;
        }
    }
}

extern "C" void kernel_launch(void* const* d_in, const int* in_sizes, int n_in,
                              void* d_out, int out_size, void* d_ws, size_t ws_size,
                              hipStream_t stream) {
    const float* x     = (const float*)d_in[0];
    const float* gnw   = (const float*)d_in[1];
    const float* gnb   = (const float*)d_in[2];
    const float* wqkv  = (const float*)d_in[3];
    const float* bqkv  = (const float*)d_in[4];
    const float* wproj = (const float*)d_in[5];
    const float* bproj = (const float*)d_in[6];
    float* out = (float*)d_out;
    float* wsf = (float*)d_ws;

    u16* qtp = (u16*)d_ws + U16_BASE;
    u16* ktp = qtp + QT_ELEMS;
    u16* vbp = ktp + QT_ELEMS;
    u16* ybp = vbp + V_ELEMS;
    u16* wbp = ybp + Y_ELEMS;
    u16* wqb = wbp + WP_ELEMS;
    u16* xnp = wqb + WQ_ELEMS;

    k_stats_partial<<<dim3(64, 8), 256, 0, stream>>>(x, wsf);
    k_stats_final<<<8, 64, 0, stream>>>(wsf);
    k_cvt2<<<328, 256, 0, stream>>>(wproj, wqkv, wbp, wqb);
    k_prep<<<dim3(64, 8, 8), 256, 0, stream>>>(x, gnw, gnb, wsf, xnp, ybp);
    k_qkv<<<dim3(16, 9, 8), 256, 0, stream>>>(xnp, wqb, bqkv, qtp, ktp, vbp);
    k_attn_pv<<<512, 512, 0, stream>>>(qtp, ktp, vbp, ybp);
    k_proj_mfma<<<dim3(32, 4, 8), 256, 0, stream>>>(wbp, ybp, bproj, out);
}

// Round 18
// 184.103 us; speedup vs baseline: 1.0536x; 1.0237x over previous
//
#include <hip/hip_runtime.h>
#include <math.h>

typedef unsigned short u16;
typedef unsigned int u32;
typedef __attribute__((ext_vector_type(4))) u16 u16x4;
typedef __attribute__((ext_vector_type(8))) short bf16x8;
typedef __attribute__((ext_vector_type(4))) float f32x4;

#define MFMA16(a, b, c) __builtin_amdgcn_mfma_f32_16x16x32_bf16(a, b, c, 0, 0, 0)

namespace {
constexpr int BATCH = 8;
constexpr int CDIM  = 512;
constexpr int PD    = 256;
constexpr int NPIX  = 4096;
constexpr int NTOT  = PD * NPIX;
constexpr float LOG2E = 1.44269504088896f;

// fp32 workspace region (float offsets)
constexpr int OFF_PART = 0;       // 8*64*2
constexpr int OFF_STAT = 2048;    // 8*2

// bf16 regions (u16 offsets from ws base)
constexpr size_t U16_BASE = 139264;                      // byte 278528
constexpr size_t QT_ELEMS = (size_t)BATCH * NPIX * 16;   // 524288
constexpr size_t V_ELEMS  = (size_t)BATCH * PD * NPIX;   // 8388608
constexpr size_t Y_ELEMS  = (size_t)BATCH * NPIX * CDIM; // 16777216
constexpr size_t WP_ELEMS = (size_t)CDIM * CDIM;         // 262144
constexpr size_t WQ_ELEMS = 288 * 256;                   // 73728

// tiled layouts: addr(r, k) = (k>>3)*(R*8) + r*8 + (k&7)
// xn: R=NPIX, K=PD   -> kblk stride 32768
// y : R=NPIX, K=CDIM -> kblk stride 32768
// wb: R=CDIM, K=CDIM -> kblk stride 4096
// wq: R=288,  K=PD   -> kblk stride 2304
// v : R=PD,   K=NPIX -> kblk stride 2048
} // namespace

__device__ __forceinline__ u16 f2bf(float f) {
    union { float f; u32 u; } v; v.f = f;
    return (u16)((v.u + 0x7fffu + ((v.u >> 16) & 1u)) >> 16);
}
__device__ __forceinline__ u32 cvtpk(float lo, float hi) {
    u32 r;
    asm("v_cvt_pk_bf16_f32 %0, %1, %2" : "=v"(r) : "v"(lo), "v"(hi));
    return r;
}
// native 2^x via intrinsic: single v_exp_f32 with proper TRANS hazard handling
__device__ __forceinline__ float fexp2(float x) {
    return __builtin_amdgcn_exp2f(x);
}

// ---------------- K1a: per-chunk partial sums for GroupNorm stats ----------
__global__ __launch_bounds__(256) void k_stats_partial(const float* __restrict__ x,
                                                       float* __restrict__ ws) {
    int b = blockIdx.y, chunk = blockIdx.x, t = threadIdx.x;
    const float4* x4 = reinterpret_cast<const float4*>(
        x + (size_t)b * CDIM * NPIX + (size_t)chunk * 16384);
    float s = 0.f, sq = 0.f;
#pragma unroll
    for (int i = 0; i < 16; ++i) {
        float4 v = x4[i * 256 + t];
        s  += v.x + v.y + v.z + v.w;
        sq += v.x * v.x + v.y * v.y + v.z * v.z + v.w * v.w;
    }
    for (int off = 32; off; off >>= 1) {
        s  += __shfl_down(s, off);
        sq += __shfl_down(sq, off);
    }
    __shared__ float red[8];
    int wid = t >> 6, lane = t & 63;
    if (lane == 0) { red[wid * 2] = s; red[wid * 2 + 1] = sq; }
    __syncthreads();
    if (t == 0) {
        float S = red[0] + red[2] + red[4] + red[6];
        float Q = red[1] + red[3] + red[5] + red[7];
        ws[OFF_PART + (b * 64 + chunk) * 2]     = S;
        ws[OFF_PART + (b * 64 + chunk) * 2 + 1] = Q;
    }
}

__global__ __launch_bounds__(64) void k_stats_final(float* __restrict__ ws) {
    int b = blockIdx.x, t = threadIdx.x;
    float s = ws[OFF_PART + (b * 64 + t) * 2];
    float q = ws[OFF_PART + (b * 64 + t) * 2 + 1];
    for (int off = 32; off; off >>= 1) {
        s += __shfl_down(s, off);
        q += __shfl_down(q, off);
    }
    if (t == 0) {
        float mean = s / (float)NTOT;
        float var  = q / (float)NTOT - mean * mean;
        ws[OFF_STAT + b * 2]     = mean;
        ws[OFF_STAT + b * 2 + 1] = rsqrtf(var + 1e-5f);
    }
}

// ------- merged fp32 -> bf16 convert into TILED layouts (wproj, wqkv) ------
__global__ __launch_bounds__(256) void k_cvt2(const float* __restrict__ wp,
                                              const float* __restrict__ wq,
                                              u16* __restrict__ wpb,
                                              u16* __restrict__ wqb) {
    int bx = blockIdx.x, t = threadIdx.x;
    if (bx < 256) {
        int i = bx * 1024 + t * 4;        // linear over [512][512]
        int o = i >> 9, k = i & 511;
        float4 v = *reinterpret_cast<const float4*>(wp + i);
        u16x4 out;
        out.x = f2bf(v.x); out.y = f2bf(v.y); out.z = f2bf(v.z); out.w = f2bf(v.w);
        *reinterpret_cast<u16x4*>(wpb + (k >> 3) * 4096 + o * 8 + (k & 7)) = out;
    } else {
        int i = (bx - 256) * 1024 + t * 4; // linear over [288][256]
        int o = i >> 8, k = i & 255;
        float4 v = *reinterpret_cast<const float4*>(wq + i);
        u16x4 out;
        out.x = f2bf(v.x); out.y = f2bf(v.y); out.z = f2bf(v.z); out.w = f2bf(v.w);
        *reinterpret_cast<u16x4*>(wqb + (k >> 3) * 2304 + o * 8 + (k & 7)) = out;
    }
}

// ------- K2: prep = GroupNorm(x1)->xn(tiled)  AND  silu(x2)->y(tiled) ------
__global__ __launch_bounds__(256) void k_prep(const float* __restrict__ x,
        const float* __restrict__ gnw, const float* __restrict__ gnb,
        const float* __restrict__ wsf, u16* __restrict__ xn, u16* __restrict__ yb) {
    int b = blockIdx.z, yy = blockIdx.y, n0 = blockIdx.x * 64, t = threadIdx.x;
    __shared__ u16 T[64][72];
    int c = t >> 2, nb = (t & 3) * 16;
    if (yy < 4) {
        int ca = yy * 64 + c;
        float mu = wsf[OFF_STAT + b * 2], rs = wsf[OFF_STAT + b * 2 + 1];
        float a = rs * gnw[ca];
        float sh = gnb[ca] - mu * a;
        const float* xb = x + ((size_t)b * CDIM + ca) * NPIX;
#pragma unroll
        for (int j = 0; j < 4; ++j) {
            float4 v = *reinterpret_cast<const float4*>(xb + n0 + nb + j * 4);
            T[nb + j * 4 + 0][c] = f2bf(v.x * a + sh);
            T[nb + j * 4 + 1][c] = f2bf(v.y * a + sh);
            T[nb + j * 4 + 2][c] = f2bf(v.z * a + sh);
            T[nb + j * 4 + 3][c] = f2bf(v.w * a + sh);
        }
        __syncthreads();
        int n = n0 + (t >> 2), cb = (t & 3) * 16;
        u16* dstb = xn + (size_t)b * NPIX * PD;
#pragma unroll
        for (int j = 0; j < 4; ++j) {
            int cg = yy * 64 + cb + j * 4;
            *reinterpret_cast<u16x4*>(dstb + (size_t)(cg >> 3) * 32768 + n * 8 + (cg & 7)) =
                *reinterpret_cast<u16x4*>(&T[t >> 2][cb + j * 4]);
        }
    } else {
        int c0 = (yy - 4) * 64;
        const float* xb = x + ((size_t)b * CDIM + PD + c0 + c) * NPIX;
#pragma unroll
        for (int j = 0; j < 4; ++j) {
            float4 v = *reinterpret_cast<const float4*>(xb + n0 + nb + j * 4);
            T[nb + j * 4 + 0][c] = f2bf(v.x / (1.f + __expf(-v.x)));
            T[nb + j * 4 + 1][c] = f2bf(v.y / (1.f + __expf(-v.y)));
            T[nb + j * 4 + 2][c] = f2bf(v.z / (1.f + __expf(-v.z)));
            T[nb + j * 4 + 3][c] = f2bf(v.w / (1.f + __expf(-v.w)));
        }
        __syncthreads();
        int n = n0 + (t >> 2), cb = (t & 3) * 16;
        u16* dstb = yb + (size_t)b * NPIX * CDIM;
#pragma unroll
        for (int j = 0; j < 4; ++j) {
            int cg = PD + c0 + cb + j * 4;
            *reinterpret_cast<u16x4*>(dstb + (size_t)(cg >> 3) * 32768 + n * 8 + (cg & 7)) =
                *reinterpret_cast<u16x4*>(&T[t >> 2][cb + j * 4]);
        }
    }
}

// ---------------- K3: qkv = w_qkv_bf16 @ xn (MFMA, tiled reads) ------------
__global__ __launch_bounds__(256) void k_qkv(const u16* __restrict__ xn,
        const u16* __restrict__ wq, const float* __restrict__ bqkv,
        u16* __restrict__ qt, u16* __restrict__ kt, u16* __restrict__ vb) {
    int b = blockIdx.z, o0 = blockIdx.y * 32, n0 = blockIdx.x * 256;
    int t = threadIdx.x, w = t >> 6, l = t & 63, lg = l >> 4, lr = l & 15;
    int nbase = n0 + w * 64;
    const u16* xnb = xn + (size_t)b * NPIX * PD;
    const f32x4 z4 = {0.f, 0.f, 0.f, 0.f};
    f32x4 acc[2][4];
#pragma unroll
    for (int i = 0; i < 2; ++i)
#pragma unroll
        for (int j = 0; j < 4; ++j) acc[i][j] = z4;

#pragma unroll
    for (int k0 = 0; k0 < PD; k0 += 32) {
        bf16x8 xf[4], wf[2];
#pragma unroll
        for (int nf = 0; nf < 4; ++nf)
            xf[nf] = *reinterpret_cast<const bf16x8*>(
                xnb + (size_t)((k0 >> 3) + lg) * 32768 + (nbase + nf * 16 + lr) * 8);
#pragma unroll
        for (int of = 0; of < 2; ++of)
            wf[of] = *reinterpret_cast<const bf16x8*>(
                wq + (size_t)((k0 >> 3) + lg) * 2304 + (o0 + of * 16 + lr) * 8);
#pragma unroll
        for (int of = 0; of < 2; ++of)
#pragma unroll
            for (int nf = 0; nf < 4; ++nf)
                acc[of][nf] = MFMA16(xf[nf], wf[of], acc[of][nf]);
    }

    if (o0 == 0) {
#pragma unroll
        for (int of = 0; of < 2; ++of) {
            int o = of * 16 + lr;
            float bias = bqkv[o];
            float sc = (of == 0) ? 0.25f * LOG2E : 1.0f;
            u16* dst = (of == 0) ? (qt + (size_t)b * NPIX * 16 + lr)
                                 : (kt + (size_t)b * NPIX * 16 + lr);
#pragma unroll
            for (int nf = 0; nf < 4; ++nf) {
#pragma unroll
                for (int r = 0; r < 4; ++r) {
                    int n = nbase + nf * 16 + 4 * lg + r;
                    dst[(size_t)n * 16] = f2bf((acc[of][nf][r] + bias) * sc);
                }
            }
        }
    } else {
        u16* vout = vb + (size_t)b * PD * NPIX;
#pragma unroll
        for (int of = 0; of < 2; ++of) {
            int c = o0 - 32 + of * 16 + lr;
            float bias = bqkv[32 + c];
#pragma unroll
            for (int nf = 0; nf < 4; ++nf) {
                u16x4 pw;
                pw.x = f2bf(acc[of][nf][0] + bias);
                pw.y = f2bf(acc[of][nf][1] + bias);
                pw.z = f2bf(acc[of][nf][2] + bias);
                pw.w = f2bf(acc[of][nf][3] + bias);
                // v tiled: elem(c, n) at (n>>3)*2048 + c*8 + (n&7)
                int nblk = (nbase >> 3) + nf * 2 + (lg >> 1);
                *reinterpret_cast<u16x4*>(
                    vout + (size_t)nblk * 2048 + c * 8 + (lg & 1) * 4) = pw;
            }
        }
    }
}

// ---------------- K4: fused flash PV (r15 exact: the 110 us optimum) -------
__global__ __launch_bounds__(512) void k_attn_pv(const u16* __restrict__ qt,
        const u16* __restrict__ kt, const u16* __restrict__ vb,
        u16* __restrict__ yb) {
    int bid = blockIdx.x;
    int b = bid & 7, q0 = (bid >> 3) * 64;
    int t = threadIdx.x, w = t >> 6, l = t & 63, lg = l >> 4, lr = l & 15;
    int band = w & 3, mfb = w >> 2; // wave scores band `band`, mf in {mfb, mfb+2}
    __shared__ u16 Pl[16384];      // flat: [buf 8192][half 4096][n*64+m swizzled]
    __shared__ float Ls[2][64];

    const u16* Qt = qt + ((size_t)b * NPIX + q0) * 16;

    const bf16x8 zf = {0, 0, 0, 0, 0, 0, 0, 0};
    bf16x8 qf = zf;
    if (lg < 2)
        qf = *reinterpret_cast<const bf16x8*>(Qt + (band * 16 + lr) * 16 + lg * 8);

    // hoisted pointers (stepped per iteration)
    const u16* kp  = kt + (size_t)b * NPIX * 16 + (size_t)(mfb * 16 + lr) * 16 + lg * 8;
    // V tiled: elem(c, m) at (m>>3)*2048 + c*8 + (m&7); lane reads m = .. + lg*8
    const u16* vp0 = vb + (size_t)b * PD * NPIX + lg * 2048 + (size_t)(w * 32 + lr) * 8;
    const u16* vp1 = vp0 + 128; // +16 c

    float lp = 0.f;
    const f32x4 z4 = {0.f, 0.f, 0.f, 0.f};
    f32x4 acc[2][4];
#pragma unroll
    for (int cf = 0; cf < 2; ++cf)
#pragma unroll
        for (int nf = 0; nf < 4; ++nf) acc[cf][nf] = z4;

    int n = band * 16 + lr;
    int swz = (n & 7) << 3;
    int wrb = (n * 64 + mfb * 16 + 4 * lg) ^ swz; // f-variant: ^(i*32), +h*4096

    int bufo = 0;
    for (int it = 0; it < 32; ++it) {
        // ---- scores S^T = K·Q^T: 4 frags (2 halves x 2 mf) ----
#pragma unroll
        for (int f = 0; f < 4; ++f) {
            int h = f >> 1, i = f & 1;
            bf16x8 kf = zf;
            if (lg < 2)
                kf = *reinterpret_cast<const bf16x8*>(kp + h * 1024 + i * 512);
            f32x4 s = MFMA16(kf, qf, z4);
            float p0 = fexp2(s[0]);
            float p1 = fexp2(s[1]);
            float p2 = fexp2(s[2]);
            float p3 = fexp2(s[3]);
            lp += (p0 + p1) + (p2 + p3);
            uint2 pw;
            pw.x = cvtpk(p0, p1);
            pw.y = cvtpk(p2, p3);
            *reinterpret_cast<uint2*>(
                &Pl[bufo + h * 4096 + (wrb ^ (i * 32))]) = pw;
        }
        __syncthreads(); // P ready
        // ---- PV over 4 slices (h, ks): acc[c][n] += V[c][m] * P[n][m] ----
#pragma unroll
        for (int sl = 0; sl < 4; ++sl) {
            int h = sl >> 1, ks = sl & 1;
            bf16x8 vf0 = *reinterpret_cast<const bf16x8*>(
                vp0 + (h * 8 + ks * 4) * 2048);
            bf16x8 vf1 = *reinterpret_cast<const bf16x8*>(
                vp1 + (h * 8 + ks * 4) * 2048);
#pragma unroll
            for (int nf = 0; nf < 4; ++nf) {
                int nn = nf * 16 + lr;
                bf16x8 pf = *reinterpret_cast<const bf16x8*>(
                    &Pl[bufo + h * 4096 +
                        ((nn * 64 + ks * 32 + lg * 8) ^ ((nn & 7) << 3))]);
                acc[0][nf] = MFMA16(vf0, pf, acc[0][nf]);
                acc[1][nf] = MFMA16(vf1, pf, acc[1][nf]);
            }
        }
        kp += 2048; vp0 += 32768; vp1 += 32768;
        bufo ^= 8192;
    }
    // ---- finalize L: lane partial covers its (lg, mf-pair) m-slices ----
    lp += __shfl_xor(lp, 16);
    lp += __shfl_xor(lp, 32);
    if (l < 16) Ls[mfb][band * 16 + l] = lp; // waves mfb=0/1 hold complementary mf
    __syncthreads();
    float invl[4];
#pragma unroll
    for (int nf = 0; nf < 4; ++nf)
        invl[nf] = 1.f / (Ls[0][nf * 16 + lr] + Ls[1][nf * 16 + lr]);
    // ---- epilogue: /L, SiLU, write y TILED: (c>>3)*32768 + n*8 + (c&7) ----
    u16* ybase = yb + (size_t)b * NPIX * CDIM;
#pragma unroll
    for (int nf = 0; nf < 4; ++nf) {
        int nq = q0 + nf * 16 + lr;
#pragma unroll
        for (int cf = 0; cf < 2; ++cf) {
            int cg = w * 32 + cf * 16 + 4 * lg;
            u16x4 pw;
#pragma unroll
            for (int r = 0; r < 4; ++r) {
                float v = acc[cf][nf][r] * invl[nf];
                pw[r] = f2bf(v / (1.f + __expf(-v)));
            }
            *reinterpret_cast<u16x4*>(
                ybase + (size_t)(cg >> 3) * 32768 + nq * 8 + (cg & 7)) = pw;
        }
    }
}

// -------- K6: out = w_proj_bf16 @ y_bf16 + b_proj (MFMA, tiled reads) ------
__global__ __launch_bounds__(256) void k_proj_mfma(const u16* __restrict__ wb,
        const u16* __restrict__ yb, const float* __restrict__ bproj,
        float* __restrict__ out) {
    int b = blockIdx.z, n0 = blockIdx.x * 128, o0 = blockIdx.y * 128;
    int t = threadIdx.x, w = t >> 6, l = t & 63, lg = l >> 4, lr = l & 15;
    int wo = w & 1, wn = w >> 1;
    int obase = o0 + wo * 64, nbase = n0 + wn * 64;
    const u16* ybb = yb + (size_t)b * NPIX * CDIM;
    const f32x4 z4 = {0.f, 0.f, 0.f, 0.f};
    f32x4 acc[4][4];
#pragma unroll
    for (int i = 0; i < 4; ++i)
#pragma unroll
        for (int j = 0; j < 4; ++j) acc[i][j] = z4;

    for (int k0 = 0; k0 < CDIM; k0 += 32) {
        bf16x8 af[4], bfr[4];
#pragma unroll
        for (int of = 0; of < 4; ++of)
            af[of] = *reinterpret_cast<const bf16x8*>(
                wb + (size_t)((k0 >> 3) + lg) * 4096 + (obase + of * 16 + lr) * 8);
#pragma unroll
        for (int nf = 0; nf < 4; ++nf)
            bfr[nf] = *reinterpret_cast<const bf16x8*>(
                ybb + (size_t)((k0 >> 3) + lg) * 32768 + (nbase + nf * 16 + lr) * 8);
#pragma unroll
        for (int of = 0; of < 4; ++of)
#pragma unroll
            for (int nf = 0; nf < 4; ++nf)
                acc[of][nf] = MFMA16(af[of], bfr[nf], acc[of][nf]);
    }
#pragma unroll
    for (int of = 0; of < 4; ++of) {
        int o = obase + of * 16 + 4 * lg;
#pragma unroll
        for (int r = 0; r < 4; ++r) {
            float bb = bproj[o + r];
#pragma unroll
            for (int nf = 0; nf < 4; ++nf)
                out[((size_t)b * CDIM + o + r) * NPIX + nbase + nf * 16 + lr] =
                    acc[of][nf][r] + bb;
        }
    }
}

extern "C" void kernel_launch(void* const* d_in, const int* in_sizes, int n_in,
                              void* d_out, int out_size, void* d_ws, size_t ws_size,
                              hipStream_t stream) {
    const float* x     = (const float*)d_in[0];
    const float* gnw   = (const float*)d_in[1];
    const float* gnb   = (const float*)d_in[2];
    const float* wqkv  = (const float*)d_in[3];
    const float* bqkv  = (const float*)d_in[4];
    const float* wproj = (const float*)d_in[5];
    const float* bproj = (const float*)d_in[6];
    float* out = (float*)d_out;
    float* wsf = (float*)d_ws;

    u16* qtp = (u16*)d_ws + U16_BASE;
    u16* ktp = qtp + QT_ELEMS;
    u16* vbp = ktp + QT_ELEMS;
    u16* ybp = vbp + V_ELEMS;
    u16* wbp = ybp + Y_ELEMS;
    u16* wqb = wbp + WP_ELEMS;
    u16* xnp = wqb + WQ_ELEMS;

    k_stats_partial<<<dim3(64, 8), 256, 0, stream>>>(x, wsf);
    k_stats_final<<<8, 64, 0, stream>>>(wsf);
    k_cvt2<<<328, 256, 0, stream>>>(wproj, wqkv, wbp, wqb);
    k_prep<<<dim3(64, 8, 8), 256, 0, stream>>>(x, gnw, gnb, wsf, xnp, ybp);
    k_qkv<<<dim3(16, 9, 8), 256, 0, stream>>>(xnp, wqb, bqkv, qtp, ktp, vbp);
    k_attn_pv<<<512, 512, 0, stream>>>(qtp, ktp, vbp, ybp);
    k_proj_mfma<<<dim3(32, 4, 8), 256, 0, stream>>>(wbp, ybp, bproj, out);
}